// Round 7
// baseline (38.940 us; speedup 1.0000x reference)
//
#include <hip/hip_runtime.h>
#include <math.h>

#define BS 8
#define N_PTS 8192
#define N_SAMPLES 2048
#define TA 512                    // threads in min kernel (8 waves/block)
#define SPT 4                     // samples per thread: 512*4 = 2048 = full batch
#define PSPLIT 64
#define CHUNK (N_PTS / PSPLIT)    // 128 points per block
#define NPAIR (CHUNK / 2)         // 64 point-pairs per side

// ws layout: part[2][BS][PSPLIT][N_SAMPLES] floats (8 MiB), then tsum[16]
#define PART_ELEMS (2 * BS * PSPLIT * N_SAMPLES)

typedef float v2f __attribute__((ext_vector_type(2)));

#if !defined(__has_builtin) || !__has_builtin(__builtin_elementwise_fma)
static __device__ inline v2f pk_fma(v2f a, v2f b, v2f c) {
    v2f r; r.x = fmaf(a.x, b.x, c.x); r.y = fmaf(a.y, b.y, c.y); return r;
}
#else
#define pk_fma(a, b, c) __builtin_elementwise_fma((a), (b), (c))
#endif

// min3 forced to a single v_min3_f32 (result = min(a, b, c)); register-only asm.
static __device__ inline float min3(float a, float b, float c) {
    float r;
    asm("v_min3_f32 %0, %1, %2, %3" : "=v"(r) : "v"(a), "v"(b), "v"(c));
    return r;
}

struct __align__(16) PairT { v2f xx, yy, zz, ww; };   // {p0x,p1x},{p0y,p1y},{p0z,p1z},{|p0|^2,|p1|^2}

// Kernel A: per (batch, point-chunk) block. Metric per (sample, point):
//   f = |p|^2 - 2 s.p   (monotone in d^2 for fixed s; d^2 = f + |s|^2)
// Points staged in LDS PAIR-TRANSPOSED so two points cost 3 v_pk_fma_f32 +
// 1 v_min3_f32 per sample = 2 issue slots per pair-eval (vs 3.5 scalar).
// R0-R6 showed we are VALU-issue-bound (occupancy 2x gained ~0, atomics vs
// stores a wash) -> attack instruction count with packed fp32.
__global__ __launch_bounds__(TA, 4)
void chamfer_min_kernel(const float* __restrict__ gts,
                        const float* __restrict__ preds,
                        const float* __restrict__ grid,
                        float* __restrict__ part)
{
    const int bid = blockIdx.x;
    const int b   = bid >> 6;           // / PSPLIT
    const int pc  = bid & (PSPLIT - 1);
    const int t   = threadIdx.x;

    __shared__ PairT ldsP[NPAIR];
    __shared__ PairT ldsG[NPAIR];

    // Staging + pair-transpose in one step: threads 0..63 build pred pairs,
    // 64..127 build gts pairs. Each thread reads 6 consecutive floats.
    if (t < 2 * NPAIR) {
        const int j = t & (NPAIR - 1);
        const float* src = ((t < NPAIR) ? preds : gts)
                         + ((size_t)b * N_PTS + (size_t)pc * CHUNK + 2 * j) * 3;
        const float x0 = src[0], y0 = src[1], z0 = src[2];
        const float x1 = src[3], y1 = src[4], z1 = src[5];
        PairT pr;
        pr.xx = (v2f){x0, x1};
        pr.yy = (v2f){y0, y1};
        pr.zz = (v2f){z0, z1};
        pr.ww = (v2f){fmaf(x0, x0, fmaf(y0, y0, z0 * z0)),
                      fmaf(x1, x1, fmaf(y1, y1, z1 * z1))};
        if (t < NPAIR) ldsP[j] = pr; else ldsG[j] = pr;
    }

    // Per-thread samples (coalesced: s = k*512 + t); ns = -2*s.
    float nsx[SPT], nsy[SPT], nsz[SPT], mP[SPT], mG[SPT];
    {
        const float* grow = grid + (size_t)b * N_SAMPLES * 3;
#pragma unroll
        for (int k = 0; k < SPT; ++k) {
            const int s = k * TA + t;
            nsx[k] = -2.0f * grow[s * 3 + 0];
            nsy[k] = -2.0f * grow[s * 3 + 1];
            nsz[k] = -2.0f * grow[s * 3 + 2];
            mP[k] = 3.0e38f;
            mG[k] = 3.0e38f;
        }
    }

    __syncthreads();

    // Main loop: one point-PAIR per side per iter.
#pragma unroll 4
    for (int j = 0; j < NPAIR; ++j) {
        const PairT p = ldsP[j];
        const PairT g = ldsG[j];
#pragma unroll
        for (int k = 0; k < SPT; ++k) {
            const v2f vx = {nsx[k], nsx[k]};
            const v2f vy = {nsy[k], nsy[k]};
            const v2f vz = {nsz[k], nsz[k]};
            const v2f tp = pk_fma(p.xx, vx, pk_fma(p.yy, vy, pk_fma(p.zz, vz, p.ww)));
            mP[k] = min3(tp.x, tp.y, mP[k]);
            const v2f tg = pk_fma(g.xx, vx, pk_fma(g.yy, vy, pk_fma(g.zz, vz, g.ww)));
            mG[k] = min3(tg.x, tg.y, mG[k]);
        }
    }

    // Disjoint slices, coalesced dword streaming stores of clamped d^2.
    float* pp = part + (((size_t)b)        * PSPLIT + pc) * N_SAMPLES;
    float* pg = part + (((size_t)(BS + b)) * PSPLIT + pc) * N_SAMPLES;
#pragma unroll
    for (int k = 0; k < SPT; ++k) {
        const int s = k * TA + t;
        const float s2 = 0.25f * fmaf(nsx[k], nsx[k], fmaf(nsy[k], nsy[k], nsz[k] * nsz[k]));
        pp[s] = fmaxf(mP[k] + s2, 0.0f);
        pg[s] = fmaxf(mG[k] + s2, 0.0f);
    }
}

// Kernel B: per (batch, half-of-2048) block: float4-vectorized min over the
// 64 partials per side (1 KB/wave fully-coalesced reads), |sqrt-sqrt|,
// fixed-tree block sum -> tsum[blk]. Deterministic.
__global__ __launch_bounds__(256, 1)
void chamfer_reduce_kernel(const float* __restrict__ part,
                           float* __restrict__ tsum)
{
    const int blk  = blockIdx.x;       // 0..15
    const int b    = blk >> 1;
    const int half = blk & 1;
    const int t    = threadIdx.x;
    const int g    = half * 256 + t;   // float4 group index within 512

    const float4* pp = (const float4*)(part + ((size_t)b)        * PSPLIT * N_SAMPLES) + g;
    const float4* pg = (const float4*)(part + ((size_t)(BS + b)) * PSPLIT * N_SAMPLES) + g;

    float4 mp = make_float4(3.0e38f, 3.0e38f, 3.0e38f, 3.0e38f);
    float4 mg = mp;
#pragma unroll 8
    for (int pc = 0; pc < PSPLIT; ++pc) {
        const float4 a = pp[(size_t)pc * (N_SAMPLES / 4)];
        mp.x = fminf(mp.x, a.x); mp.y = fminf(mp.y, a.y);
        mp.z = fminf(mp.z, a.z); mp.w = fminf(mp.w, a.w);
        const float4 c = pg[(size_t)pc * (N_SAMPLES / 4)];
        mg.x = fminf(mg.x, c.x); mg.y = fminf(mg.y, c.y);
        mg.z = fminf(mg.z, c.z); mg.w = fminf(mg.w, c.w);
    }

    float v = fabsf(sqrtf(mp.x) - sqrtf(mg.x))
            + fabsf(sqrtf(mp.y) - sqrtf(mg.y))
            + fabsf(sqrtf(mp.z) - sqrtf(mg.z))
            + fabsf(sqrtf(mp.w) - sqrtf(mg.w));

#pragma unroll
    for (int off = 32; off > 0; off >>= 1)
        v += __shfl_down(v, off, 64);

    __shared__ float w[4];
    if ((t & 63) == 0) w[t >> 6] = v;
    __syncthreads();
    if (t == 0) tsum[blk] = (w[0] + w[1]) + (w[2] + w[3]);
}

// Kernel C: combine 2 half sums per batch (fixed order) -> mean.
__global__ __launch_bounds__(64)
void chamfer_out_kernel(const float* __restrict__ tsum,
                        float* __restrict__ out)
{
    const int b = threadIdx.x;
    if (b < BS)
        out[b] = (tsum[2 * b] + tsum[2 * b + 1]) * (1.0f / (float)N_SAMPLES);
}

extern "C" void kernel_launch(void* const* d_in, const int* in_sizes, int n_in,
                              void* d_out, int out_size, void* d_ws, size_t ws_size,
                              hipStream_t stream)
{
    const float* gts   = (const float*)d_in[0];
    const float* preds = (const float*)d_in[1];
    const float* grid  = (const float*)d_in[2];
    float* out  = (float*)d_out;
    float* part = (float*)d_ws;
    float* tsum = part + PART_ELEMS;

    chamfer_min_kernel<<<dim3(BS * PSPLIT), dim3(TA), 0, stream>>>(gts, preds, grid, part);
    chamfer_reduce_kernel<<<dim3(16), dim3(256), 0, stream>>>(part, tsum);
    chamfer_out_kernel<<<dim3(1), dim3(64), 0, stream>>>(tsum, out);
}